// Round 19
// baseline (592.563 us; speedup 1.0000x reference)
//
#include <hip/hip_runtime.h>
#include <hip/hip_fp16.h>

// Problem constants
#define B_  8192
#define L_  128
#define H_  256
#define A_  32
#define T_  65
#define BM  16    // batch rows per block; grid = 512

typedef _Float16 f16x8 __attribute__((ext_vector_type(8)));
typedef _Float16 f16x4 __attribute__((ext_vector_type(4)));
typedef float    f32x4 __attribute__((ext_vector_type(4)));

// rcp-based activations (R17-proven): ~1ulp, vs 2.9x absmax margin.
static __device__ __forceinline__ float sigm(float x) {
  return __builtin_amdgcn_rcpf(1.f + __expf(-x));
}
static __device__ __forceinline__ float tanh_f(float x) {
  return 1.f - 2.f * __builtin_amdgcn_rcpf(1.f + __expf(2.f * x));
}

// h-tile LDS swizzle: element (m, c) of a [BM][256] fp16 tile stored at
// byte m*512 + ((2c) ^ ((m&7)<<4)).
static __device__ __forceinline__ uint32_t hoff(int m, uint32_t byte_in_row) {
  return (uint32_t)(m * 512) + (byte_in_row ^ (uint32_t)((m & 7) << 4));
}

// A/B fragment read (16x16x32 f16): lane holds row=row, k = kt*32 + 8*g + [0..8)
static __device__ __forceinline__ f16x8 ldFrag(const _Float16* buf, int row, int g, int kt) {
  return *(const f16x8*)((const char*)buf + hoff(row, (uint32_t)(kt * 64 + g * 16)));
}
static __device__ __forceinline__ void stH(_Float16* buf, int m, int c, float v) {
  *(_Float16*)((char*)buf + hoff(m, 2u * (uint32_t)c)) = (_Float16)v;
}

// ---------------- prep kernels (identical to R17 passing version) ----------------

__global__ void prep_convert(const float* __restrict__ latent, const float* __restrict__ Whh,
                             _Float16* __restrict__ latent16, _Float16* __restrict__ Whh16) {
  const int tid = blockIdx.x * blockDim.x + threadIdx.x;
  const int stride = gridDim.x * blockDim.x;
  for (int i = tid; i < B_ * L_; i += stride) latent16[i] = (_Float16)latent[i];
  for (int i = tid; i < 768 * H_; i += stride) Whh16[i] = (_Float16)Whh[i];
}

__global__ void prep_transpose(const float* __restrict__ Wd0, const float* __restrict__ Wd1,
                               const float* __restrict__ Wd2, const float* __restrict__ Wp1,
                               const float* __restrict__ Wp2,
                               _Float16* __restrict__ Wd0T, _Float16* __restrict__ Wd1T,
                               _Float16* __restrict__ Wd2T, _Float16* __restrict__ Wp1T,
                               _Float16* __restrict__ Wp2T) {
  const int tid = blockIdx.x * blockDim.x + threadIdx.x;
  const int stride = gridDim.x * blockDim.x;
  for (int i = tid; i < 256 * 128; i += stride) { int n = i / 128, k = i % 128; Wd0T[i] = (_Float16)Wd0[k * 256 + n]; }
  for (int i = tid; i < 256 * 256; i += stride) { int n = i / 256, k = i % 256; Wd1T[i] = (_Float16)Wd1[k * 256 + n]; }
  for (int i = tid; i < 256 * 256; i += stride) { int n = i / 256, k = i % 256; Wd2T[i] = (_Float16)Wd2[k * 256 + n]; }
  for (int i = tid; i < 32 * 256;  i += stride) { int n = i / 256, k = i % 256; Wp1T[i] = (_Float16)Wp1[k * 32 + n]; }
  for (int i = tid; i < 32 * 32;   i += stride) { int n = i / 32,  k = i % 32;  Wp2T[i] = (_Float16)Wp2[k * 32 + n]; }
}

// Packed gate table: G4[a][c][j] (f16), j=0: r (b_ih+b_hh folded), j=1: z
// (b_ih+b_hh folded), j=2: n (b_ih only), j=3: pad.  One 8B load per cell.
__global__ void prep_g4(const float* __restrict__ embed, const float* __restrict__ W_ih,
                        const float* __restrict__ b_ih, const float* __restrict__ b_hh,
                        _Float16* __restrict__ G4) {
  const int idx = blockIdx.x * blockDim.x + threadIdx.x;   // a*1024 + c*4 + j
  if (idx >= A_ * 256 * 4) return;
  const int j = idx & 3, c = (idx >> 2) & 255, a = idx >> 10;
  if (j == 3) { G4[idx] = (_Float16)0.f; return; }
  const int cc = j * 256 + c;
  float s = b_ih[cc] + (j < 2 ? b_hh[cc] : 0.f);
#pragma unroll
  for (int e = 0; e < 8; ++e) s += embed[a * 8 + e] * W_ih[cc * 8 + e];
  G4[idx] = (_Float16)s;
}

// ---------------- main fused decoder kernel ----------------
// R17 base (588us best): grid 512, 256 threads = 4 waves, wr[12][8]
// register-resident W_hh, phase-top batched G4 gathers, per-q MFMA/cell
// pipeline, hold-in-regs, rcp activations.
// CHANGE vs R17: wave-split projection, ONE barrier/step.  After the main
// barrier: waves 0-1 do proj1(t) -> o1[t&1]; waves 2-3 CONCURRENTLY do
// proj2(t-1) from o1[(t-1)&1].  The o1-visibility barrier is replaced by
// the next step's main barrier (RAW/WAR both ordered by it).  Epilogue:
// barrier + proj2(T-1).

__global__ __launch_bounds__(256, 1) void decoder_main(
    const _Float16* __restrict__ latent16, const int* __restrict__ target,
    const _Float16* __restrict__ Whh16, const _Float16* __restrict__ G4,
    const _Float16* __restrict__ Wd0T, const _Float16* __restrict__ Wd1T,
    const _Float16* __restrict__ Wd2T, const _Float16* __restrict__ Wp1T,
    const _Float16* __restrict__ Wp2T,
    const float* __restrict__ bd0, const float* __restrict__ bd1, const float* __restrict__ bd2,
    const float* __restrict__ b_hh, const float* __restrict__ bp1, const float* __restrict__ bp2,
    float* __restrict__ out) {
  __shared__ _Float16 hbuf[2][BM * 256];    // 16 KB, swizzled
  __shared__ int      tok_lds[BM * T_];     // 4.2 KB
  __shared__ _Float16 o1_lds[2][BM * 40];   // 2.6 KB, parity dbuf

  const int tid = threadIdx.x;
  const int w  = tid >> 6;       // wave 0..3
  const int l  = tid & 63;
  const int lo = l & 15;
  const int g  = l >> 4;
  const int b0 = blockIdx.x * BM;

  for (int i = tid; i < BM * T_; i += 256) {
    const int m = i / T_, t = i % T_;
    tok_lds[i] = (t == 0) ? 0 : target[(size_t)(b0 + m) * T_ + (t - 1)];
  }

  float hold[4][4];   // this lane's h cells (rows 4g+i, cols w*64+q*16+lo)

  // ---------- MLP: h0 = relu(relu(latent@Wd0+bd0)@Wd1+bd1)@Wd2+bd2 ----------
  { // GEMM1 (K=128) -> hbuf[0]
    f16x8 af[4];
#pragma unroll
    for (int kt = 0; kt < 4; ++kt)
      af[kt] = *(const f16x8*)(latent16 + (size_t)(b0 + lo) * 128 + kt * 32 + g * 8);
    f32x4 acc[4] = {};
#pragma unroll
    for (int q = 0; q < 4; ++q) {
      const _Float16* bb = Wd0T + (size_t)(w * 64 + q * 16 + lo) * 128 + g * 8;
#pragma unroll
      for (int kt = 0; kt < 4; ++kt) {
        f16x8 bf = *(const f16x8*)(bb + kt * 32);
        acc[q] = __builtin_amdgcn_mfma_f32_16x16x32_f16(af[kt], bf, acc[q], 0, 0, 0);
      }
    }
#pragma unroll
    for (int q = 0; q < 4; ++q) {
      const int n = w * 64 + q * 16 + lo;
      const float bv = bd0[n];
#pragma unroll
      for (int i = 0; i < 4; ++i)
        stH(hbuf[0], 4 * g + i, n, fmaxf(acc[q][i] + bv, 0.f));
    }
  }
  __syncthreads();
  { // GEMM2 (K=256) hbuf[0] -> hbuf[1]
    f16x8 af[8];
#pragma unroll
    for (int kt = 0; kt < 8; ++kt) af[kt] = ldFrag(hbuf[0], lo, g, kt);
    f32x4 acc[4] = {};
#pragma unroll
    for (int q = 0; q < 4; ++q) {
      const _Float16* bb = Wd1T + (size_t)(w * 64 + q * 16 + lo) * 256 + g * 8;
#pragma unroll
      for (int kt = 0; kt < 8; ++kt) {
        f16x8 bf = *(const f16x8*)(bb + kt * 32);
        acc[q] = __builtin_amdgcn_mfma_f32_16x16x32_f16(af[kt], bf, acc[q], 0, 0, 0);
      }
    }
#pragma unroll
    for (int q = 0; q < 4; ++q) {
      const int n = w * 64 + q * 16 + lo;
      const float bv = bd1[n];
#pragma unroll
      for (int i = 0; i < 4; ++i)
        stH(hbuf[1], 4 * g + i, n, fmaxf(acc[q][i] + bv, 0.f));
    }
  }
  __syncthreads();
  { // GEMM3 (K=256, no relu) hbuf[1] -> hbuf[0] (initial hidden) + seed hold
    f16x8 af[8];
#pragma unroll
    for (int kt = 0; kt < 8; ++kt) af[kt] = ldFrag(hbuf[1], lo, g, kt);
    f32x4 acc[4] = {};
#pragma unroll
    for (int q = 0; q < 4; ++q) {
      const _Float16* bb = Wd2T + (size_t)(w * 64 + q * 16 + lo) * 256 + g * 8;
#pragma unroll
      for (int kt = 0; kt < 8; ++kt) {
        f16x8 bf = *(const f16x8*)(bb + kt * 32);
        acc[q] = __builtin_amdgcn_mfma_f32_16x16x32_f16(af[kt], bf, acc[q], 0, 0, 0);
      }
    }
    __syncthreads();
#pragma unroll
    for (int q = 0; q < 4; ++q) {
      const int n = w * 64 + q * 16 + lo;
      const float bv = bd2[n];
#pragma unroll
      for (int i = 0; i < 4; ++i) {
        const float hv = acc[q][i] + bv;
        stH(hbuf[0], 4 * g + i, n, hv);
        hold[i][q] = hv;                 // seed register-held h cells
      }
    }
  }
  __syncthreads();

  // ---- hoist this wave's full W_hh slice into registers: 12 x 8 f16x8 ----
  f16x8 wr[12][8];
#pragma unroll
  for (int gt = 0; gt < 3; ++gt)
#pragma unroll
    for (int q = 0; q < 4; ++q)
#pragma unroll
      for (int kt = 0; kt < 8; ++kt)
        wr[gt * 4 + q][kt] =
            *(const f16x8*)(Whh16 + (size_t)(gt * 256 + w * 64 + q * 16 + lo) * 256 + kt * 32 + g * 8);

  float bhn[4];
#pragma unroll
  for (int q = 0; q < 4; ++q) bhn[q] = b_hh[512 + w * 64 + q * 16 + lo];
  // proj role split: waves 0-1 = proj1 tile at1 = w; waves 2-3 = proj2 tile at2 = w-2
  const int at1 = w;            // valid for w<2
  const int at2 = w - 2;        // valid for w>=2
  float bp1v = 0.f, bp2v = 0.f;
  f16x8 wp2f = {};
  if (w < 2) {
    bp1v = bp1[at1 * 16 + lo];
  } else {
    bp2v = bp2[at2 * 16 + lo];
    wp2f = *(const f16x8*)(Wp2T + (at2 * 16 + lo) * 32 + g * 8);
  }

  // ---------- GRU time loop: ONE barrier/step, zero weight traffic ----------
#pragma unroll 1
  for (int t = 0; t < T_; ++t) {
    const _Float16* hr = hbuf[t & 1];
    _Float16* hw = hbuf[(t & 1) ^ 1];

    // ---- phase top: tok reads, then ALL 16 G4 gathers issued up front ----
    int tk[4];
#pragma unroll
    for (int i = 0; i < 4; ++i) tk[i] = tok_lds[(4 * g + i) * T_ + t];

    f16x4 gvp[4][4];
#pragma unroll
    for (int i = 0; i < 4; ++i) {
      const _Float16* Grow = G4 + (size_t)tk[i] * 1024;
#pragma unroll
      for (int q = 0; q < 4; ++q)
        gvp[i][q] = *(const f16x4*)(Grow + (w * 64 + q * 16 + lo) * 4);
    }

    // af fully loaded once, reused by all q
    f16x8 af[8];
#pragma unroll
    for (int kt = 0; kt < 8; ++kt) af[kt] = ldFrag(hr, lo, g, kt);

    // ---- per-q pipeline: 24 MFMAs for q, then q's 4 cells ----
#pragma unroll
    for (int q = 0; q < 4; ++q) {
      f32x4 a3[3];
#pragma unroll
      for (int gt = 0; gt < 3; ++gt) a3[gt] = (f32x4){0.f, 0.f, 0.f, 0.f};
#pragma unroll
      for (int gt = 0; gt < 3; ++gt)
#pragma unroll
        for (int kt = 0; kt < 8; ++kt)
          a3[gt] = __builtin_amdgcn_mfma_f32_16x16x32_f16(af[kt], wr[gt * 4 + q][kt], a3[gt], 0, 0, 0);

      const int c = w * 64 + q * 16 + lo;
#pragma unroll
      for (int i = 0; i < 4; ++i) {
        const float r = sigm(a3[0][i] + (float)gvp[i][q][0]);
        const float z = sigm(a3[1][i] + (float)gvp[i][q][1]);
        const float nn = tanh_f((float)gvp[i][q][2] + r * (a3[2][i] + bhn[q]));
        const float hv = nn + z * (hold[i][q] - nn);
        hold[i][q] = hv;
        stH(hw, 4 * g + i, c, hv);
      }
    }
    __syncthreads();   // the ONLY barrier: h_{t+1} visible; o1(t-1) visible to w2-3

    // ---- wave-split projection (concurrent) ----
    if (w < 2) {
      // proj1(t): o1[t&1] = relu(h_new @ Wp1 + bp1), tile at1
      f32x4 accp = {};
#pragma unroll
      for (int kt = 0; kt < 8; ++kt) {
        f16x8 a1 = ldFrag(hw, lo, g, kt);
        f16x8 b1 = *(const f16x8*)(Wp1T + (size_t)(at1 * 16 + lo) * 256 + kt * 32 + g * 8);
        accp = __builtin_amdgcn_mfma_f32_16x16x32_f16(a1, b1, accp, 0, 0, 0);
      }
      const int ac = at1 * 16 + lo;
#pragma unroll
      for (int i = 0; i < 4; ++i)
        o1_lds[t & 1][(4 * g + i) * 40 + ac] = (_Float16)fmaxf(accp[i] + bp1v, 0.f);
    } else if (t > 0) {
      // proj2(t-1): out[t-1] = relu-done o1[(t-1)&1] @ Wp2 + bp2, tile at2
      f16x8 a2 = *(const f16x8*)(o1_lds[(t - 1) & 1] + lo * 40 + g * 8);
      f32x4 accl = {};
      accl = __builtin_amdgcn_mfma_f32_16x16x32_f16(a2, wp2f, accl, 0, 0, 0);
#pragma unroll
      for (int i = 0; i < 4; ++i)
        out[((size_t)(b0 + 4 * g + i) * T_ + (t - 1)) * A_ + at2 * 16 + lo] = accl[i] + bp2v;
    }
    // next step's barrier orders o1[t&1] writes (w0-1) before w2-3's reads
  }

  // ---------- epilogue: out[T-1] (o1[(T-1)&1] written by w0-1 in last step) ----------
  __syncthreads();
  if (w >= 2) {
    f16x8 a2 = *(const f16x8*)(o1_lds[(T_ - 1) & 1] + lo * 40 + g * 8);
    f32x4 accl = {};
    accl = __builtin_amdgcn_mfma_f32_16x16x32_f16(a2, wp2f, accl, 0, 0, 0);
#pragma unroll
    for (int i = 0; i < 4; ++i)
      out[((size_t)(b0 + 4 * g + i) * T_ + (T_ - 1)) * A_ + at2 * 16 + lo] = accl[i] + bp2v;
  }
}

// ---------------- launch ----------------

extern "C" void kernel_launch(void* const* d_in, const int* in_sizes, int n_in,
                              void* d_out, int out_size, void* d_ws, size_t ws_size,
                              hipStream_t stream) {
  const float* latent = (const float*)d_in[0];
  const int*   target = (const int*)d_in[1];
  const float* embed  = (const float*)d_in[2];
  const float* W_ih   = (const float*)d_in[3];
  const float* b_ih   = (const float*)d_in[4];
  const float* W_hh   = (const float*)d_in[5];
  const float* b_hh   = (const float*)d_in[6];
  const float* Wd0    = (const float*)d_in[7];
  const float* bd0    = (const float*)d_in[8];
  const float* Wd1    = (const float*)d_in[9];
  const float* bd1    = (const float*)d_in[10];
  const float* Wd2    = (const float*)d_in[11];
  const float* bd2    = (const float*)d_in[12];
  const float* Wp1    = (const float*)d_in[13];
  const float* bp1    = (const float*)d_in[14];
  const float* Wp2    = (const float*)d_in[15];
  const float* bp2    = (const float*)d_in[16];
  float* out = (float*)d_out;

  char* ws = (char*)d_ws;
  size_t off = 0;
  auto carve = [&](size_t bytes) { char* p = ws + off; off += (bytes + 255) & ~(size_t)255; return p; };
  _Float16* latent16 = (_Float16*)carve((size_t)B_ * L_ * 2);
  _Float16* Whh16    = (_Float16*)carve((size_t)768 * H_ * 2);
  _Float16* Wd0T     = (_Float16*)carve(256 * 128 * 2);
  _Float16* Wd1T     = (_Float16*)carve(256 * 256 * 2);
  _Float16* Wd2T     = (_Float16*)carve(256 * 256 * 2);
  _Float16* Wp1T     = (_Float16*)carve(32 * 256 * 2);
  _Float16* Wp2T     = (_Float16*)carve(32 * 32 * 2);
  _Float16* G4       = (_Float16*)carve(A_ * 256 * 4 * 2);

  prep_convert<<<1024, 256, 0, stream>>>(latent, W_hh, latent16, Whh16);
  prep_transpose<<<256, 256, 0, stream>>>(Wd0, Wd1, Wd2, Wp1, Wp2, Wd0T, Wd1T, Wd2T, Wp1T, Wp2T);
  prep_g4<<<(A_ * 256 * 4 + 255) / 256, 256, 0, stream>>>(embed, W_ih, b_ih, b_hh, G4);
  decoder_main<<<B_ / BM, 256, 0, stream>>>(latent16, target, Whh16, G4,
                                            Wd0T, Wd1T, Wd2T, Wp1T, Wp2T,
                                            bd0, bd1, bd2, b_hh, bp1, bp2, out);
}

// Round 20
// 585.749 us; speedup vs baseline: 1.0116x; 1.0116x over previous
//
#include <hip/hip_runtime.h>
#include <hip/hip_fp16.h>

// Problem constants
#define B_  8192
#define L_  128
#define H_  256
#define A_  32
#define T_  65
#define BM  16    // batch rows per block; grid = 512

typedef _Float16 f16x8 __attribute__((ext_vector_type(8)));
typedef _Float16 f16x4 __attribute__((ext_vector_type(4)));
typedef float    f32x4 __attribute__((ext_vector_type(4)));

// rcp-based activations: __builtin_amdgcn_rcpf is ~1ulp; error ~1e-7 vs our
// 2.9x absmax margin.  Avoids the ~10-op exact-division expansion (no fast-math).
static __device__ __forceinline__ float sigm(float x) {
  return __builtin_amdgcn_rcpf(1.f + __expf(-x));
}
static __device__ __forceinline__ float tanh_f(float x) {
  return 1.f - 2.f * __builtin_amdgcn_rcpf(1.f + __expf(2.f * x));
}

// h-tile LDS swizzle: element (m, c) of a [BM][256] fp16 tile stored at
// byte m*512 + ((2c) ^ ((m&7)<<4)).
static __device__ __forceinline__ uint32_t hoff(int m, uint32_t byte_in_row) {
  return (uint32_t)(m * 512) + (byte_in_row ^ (uint32_t)((m & 7) << 4));
}

// A/B fragment read (16x16x32 f16): lane holds row=row, k = kt*32 + 8*g + [0..8)
static __device__ __forceinline__ f16x8 ldFrag(const _Float16* buf, int row, int g, int kt) {
  return *(const f16x8*)((const char*)buf + hoff(row, (uint32_t)(kt * 64 + g * 16)));
}
static __device__ __forceinline__ void stH(_Float16* buf, int m, int c, float v) {
  *(_Float16*)((char*)buf + hoff(m, 2u * (uint32_t)c)) = (_Float16)v;
}

// ---------------- prep kernels ----------------

__global__ void prep_convert(const float* __restrict__ latent, const float* __restrict__ Whh,
                             _Float16* __restrict__ latent16, _Float16* __restrict__ Whh16) {
  const int tid = blockIdx.x * blockDim.x + threadIdx.x;
  const int stride = gridDim.x * blockDim.x;
  for (int i = tid; i < B_ * L_; i += stride) latent16[i] = (_Float16)latent[i];
  for (int i = tid; i < 768 * H_; i += stride) Whh16[i] = (_Float16)Whh[i];
}

__global__ void prep_transpose(const float* __restrict__ Wd0, const float* __restrict__ Wd1,
                               const float* __restrict__ Wd2, const float* __restrict__ Wp1,
                               const float* __restrict__ Wp2,
                               _Float16* __restrict__ Wd0T, _Float16* __restrict__ Wd1T,
                               _Float16* __restrict__ Wd2T, _Float16* __restrict__ Wp1T,
                               _Float16* __restrict__ Wp2T) {
  const int tid = blockIdx.x * blockDim.x + threadIdx.x;
  const int stride = gridDim.x * blockDim.x;
  for (int i = tid; i < 256 * 128; i += stride) { int n = i / 128, k = i % 128; Wd0T[i] = (_Float16)Wd0[k * 256 + n]; }
  for (int i = tid; i < 256 * 256; i += stride) { int n = i / 256, k = i % 256; Wd1T[i] = (_Float16)Wd1[k * 256 + n]; }
  for (int i = tid; i < 256 * 256; i += stride) { int n = i / 256, k = i % 256; Wd2T[i] = (_Float16)Wd2[k * 256 + n]; }
  for (int i = tid; i < 32 * 256;  i += stride) { int n = i / 256, k = i % 256; Wp1T[i] = (_Float16)Wp1[k * 32 + n]; }
  for (int i = tid; i < 32 * 32;   i += stride) { int n = i / 32,  k = i % 32;  Wp2T[i] = (_Float16)Wp2[k * 32 + n]; }
}

// Packed gate table: G4[a][c][j] (f16), j=0: r (b_ih+b_hh folded), j=1: z
// (b_ih+b_hh folded), j=2: n (b_ih only), j=3: pad.  One 8B load per cell.
__global__ void prep_g4(const float* __restrict__ embed, const float* __restrict__ W_ih,
                        const float* __restrict__ b_ih, const float* __restrict__ b_hh,
                        _Float16* __restrict__ G4) {
  const int idx = blockIdx.x * blockDim.x + threadIdx.x;   // a*1024 + c*4 + j
  if (idx >= A_ * 256 * 4) return;
  const int j = idx & 3, c = (idx >> 2) & 255, a = idx >> 10;
  if (j == 3) { G4[idx] = (_Float16)0.f; return; }
  const int cc = j * 256 + c;
  float s = b_ih[cc] + (j < 2 ? b_hh[cc] : 0.f);
#pragma unroll
  for (int e = 0; e < 8; ++e) s += embed[a * 8 + e] * W_ih[cc * 8 + e];
  G4[idx] = (_Float16)s;
}

// ---------------- main fused decoder kernel ----------------
// Final structure (R17, 588us): grid 512, 256 threads = 4 waves (1 wave/SIMD,
// forced by the 512-slot unified register budget), wr[12][8] register-resident
// W_hh (zero weight streaming; FETCH ~8 MB total), phase-top batched G4
// gathers, per-q MFMA/cell pipeline, hold-in-regs, rcp-based activations,
// 2-barrier fused output projection on waves 0-1.

__global__ __launch_bounds__(256, 1) void decoder_main(
    const _Float16* __restrict__ latent16, const int* __restrict__ target,
    const _Float16* __restrict__ Whh16, const _Float16* __restrict__ G4,
    const _Float16* __restrict__ Wd0T, const _Float16* __restrict__ Wd1T,
    const _Float16* __restrict__ Wd2T, const _Float16* __restrict__ Wp1T,
    const _Float16* __restrict__ Wp2T,
    const float* __restrict__ bd0, const float* __restrict__ bd1, const float* __restrict__ bd2,
    const float* __restrict__ b_hh, const float* __restrict__ bp1, const float* __restrict__ bp2,
    float* __restrict__ out) {
  __shared__ _Float16 hbuf[2][BM * 256];   // 16 KB, swizzled
  __shared__ int      tok_lds[BM * T_];    // 4.2 KB
  __shared__ _Float16 o1_lds[BM * 40];     // 1.3 KB

  const int tid = threadIdx.x;
  const int w  = tid >> 6;       // wave 0..3
  const int l  = tid & 63;
  const int lo = l & 15;
  const int g  = l >> 4;
  const int b0 = blockIdx.x * BM;

  for (int i = tid; i < BM * T_; i += 256) {
    const int m = i / T_, t = i % T_;
    tok_lds[i] = (t == 0) ? 0 : target[(size_t)(b0 + m) * T_ + (t - 1)];
  }

  float hold[4][4];   // this lane's h cells (rows 4g+i, cols w*64+q*16+lo)

  // ---------- MLP: h0 = relu(relu(latent@Wd0+bd0)@Wd1+bd1)@Wd2+bd2 ----------
  { // GEMM1 (K=128) -> hbuf[0]
    f16x8 af[4];
#pragma unroll
    for (int kt = 0; kt < 4; ++kt)
      af[kt] = *(const f16x8*)(latent16 + (size_t)(b0 + lo) * 128 + kt * 32 + g * 8);
    f32x4 acc[4] = {};
#pragma unroll
    for (int q = 0; q < 4; ++q) {
      const _Float16* bb = Wd0T + (size_t)(w * 64 + q * 16 + lo) * 128 + g * 8;
#pragma unroll
      for (int kt = 0; kt < 4; ++kt) {
        f16x8 bf = *(const f16x8*)(bb + kt * 32);
        acc[q] = __builtin_amdgcn_mfma_f32_16x16x32_f16(af[kt], bf, acc[q], 0, 0, 0);
      }
    }
#pragma unroll
    for (int q = 0; q < 4; ++q) {
      const int n = w * 64 + q * 16 + lo;
      const float bv = bd0[n];
#pragma unroll
      for (int i = 0; i < 4; ++i)
        stH(hbuf[0], 4 * g + i, n, fmaxf(acc[q][i] + bv, 0.f));
    }
  }
  __syncthreads();
  { // GEMM2 (K=256) hbuf[0] -> hbuf[1]
    f16x8 af[8];
#pragma unroll
    for (int kt = 0; kt < 8; ++kt) af[kt] = ldFrag(hbuf[0], lo, g, kt);
    f32x4 acc[4] = {};
#pragma unroll
    for (int q = 0; q < 4; ++q) {
      const _Float16* bb = Wd1T + (size_t)(w * 64 + q * 16 + lo) * 256 + g * 8;
#pragma unroll
      for (int kt = 0; kt < 8; ++kt) {
        f16x8 bf = *(const f16x8*)(bb + kt * 32);
        acc[q] = __builtin_amdgcn_mfma_f32_16x16x32_f16(af[kt], bf, acc[q], 0, 0, 0);
      }
    }
#pragma unroll
    for (int q = 0; q < 4; ++q) {
      const int n = w * 64 + q * 16 + lo;
      const float bv = bd1[n];
#pragma unroll
      for (int i = 0; i < 4; ++i)
        stH(hbuf[1], 4 * g + i, n, fmaxf(acc[q][i] + bv, 0.f));
    }
  }
  __syncthreads();
  { // GEMM3 (K=256, no relu) hbuf[1] -> hbuf[0] (initial hidden) + seed hold
    f16x8 af[8];
#pragma unroll
    for (int kt = 0; kt < 8; ++kt) af[kt] = ldFrag(hbuf[1], lo, g, kt);
    f32x4 acc[4] = {};
#pragma unroll
    for (int q = 0; q < 4; ++q) {
      const _Float16* bb = Wd2T + (size_t)(w * 64 + q * 16 + lo) * 256 + g * 8;
#pragma unroll
      for (int kt = 0; kt < 8; ++kt) {
        f16x8 bf = *(const f16x8*)(bb + kt * 32);
        acc[q] = __builtin_amdgcn_mfma_f32_16x16x32_f16(af[kt], bf, acc[q], 0, 0, 0);
      }
    }
    __syncthreads();
#pragma unroll
    for (int q = 0; q < 4; ++q) {
      const int n = w * 64 + q * 16 + lo;
      const float bv = bd2[n];
#pragma unroll
      for (int i = 0; i < 4; ++i) {
        const float hv = acc[q][i] + bv;
        stH(hbuf[0], 4 * g + i, n, hv);
        hold[i][q] = hv;                 // seed register-held h cells
      }
    }
  }
  __syncthreads();

  // ---- hoist this wave's full W_hh slice into registers: 12 x 8 f16x8 ----
  f16x8 wr[12][8];
#pragma unroll
  for (int gt = 0; gt < 3; ++gt)
#pragma unroll
    for (int q = 0; q < 4; ++q)
#pragma unroll
      for (int kt = 0; kt < 8; ++kt)
        wr[gt * 4 + q][kt] =
            *(const f16x8*)(Whh16 + (size_t)(gt * 256 + w * 64 + q * 16 + lo) * 256 + kt * 32 + g * 8);

  float bhn[4];
#pragma unroll
  for (int q = 0; q < 4; ++q) bhn[q] = b_hh[512 + w * 64 + q * 16 + lo];
  const int at = w;                        // proj tile of waves 0..1 (cols at*16)
  float bp1v = 0.f, bp2v = 0.f;
  if (w < 2) { bp1v = bp1[at * 16 + lo]; bp2v = bp2[at * 16 + lo]; }

  // ---------- GRU time loop: zero weight traffic ----------
#pragma unroll 1
  for (int t = 0; t < T_; ++t) {
    const _Float16* hr = hbuf[t & 1];
    _Float16* hw = hbuf[(t & 1) ^ 1];

    // ---- phase top: tok reads, then ALL 16 G4 gathers issued up front ----
    int tk[4];
#pragma unroll
    for (int i = 0; i < 4; ++i) tk[i] = tok_lds[(4 * g + i) * T_ + t];

    f16x4 gvp[4][4];
#pragma unroll
    for (int i = 0; i < 4; ++i) {
      const _Float16* Grow = G4 + (size_t)tk[i] * 1024;
#pragma unroll
      for (int q = 0; q < 4; ++q)
        gvp[i][q] = *(const f16x4*)(Grow + (w * 64 + q * 16 + lo) * 4);
    }

    // af fully loaded once, reused by all q
    f16x8 af[8];
#pragma unroll
    for (int kt = 0; kt < 8; ++kt) af[kt] = ldFrag(hr, lo, g, kt);

    // ---- per-q pipeline: 24 MFMAs for q, then q's 4 cells ----
#pragma unroll
    for (int q = 0; q < 4; ++q) {
      f32x4 a3[3];
#pragma unroll
      for (int gt = 0; gt < 3; ++gt) a3[gt] = (f32x4){0.f, 0.f, 0.f, 0.f};
#pragma unroll
      for (int gt = 0; gt < 3; ++gt)
#pragma unroll
        for (int kt = 0; kt < 8; ++kt)
          a3[gt] = __builtin_amdgcn_mfma_f32_16x16x32_f16(af[kt], wr[gt * 4 + q][kt], a3[gt], 0, 0, 0);

      const int c = w * 64 + q * 16 + lo;
#pragma unroll
      for (int i = 0; i < 4; ++i) {
        const float r = sigm(a3[0][i] + (float)gvp[i][q][0]);
        const float z = sigm(a3[1][i] + (float)gvp[i][q][1]);
        const float nn = tanh_f((float)gvp[i][q][2] + r * (a3[2][i] + bhn[q]));
        const float hv = nn + z * (hold[i][q] - nn);
        hold[i][q] = hv;
        stH(hw, 4 * g + i, c, hv);
      }
    }
    __syncthreads();   // h_{t+1} visible

    // ---- fused projection (2 barriers, waves 0..1) ----
    if (w < 2) { // stage-1: o1 = relu(h_new @ Wp1 + bp1), cols at*16..
      f32x4 accp = {};
#pragma unroll
      for (int kt = 0; kt < 8; ++kt) {
        f16x8 a1 = ldFrag(hw, lo, g, kt);
        f16x8 b1 = *(const f16x8*)(Wp1T + (size_t)(at * 16 + lo) * 256 + kt * 32 + g * 8);
        accp = __builtin_amdgcn_mfma_f32_16x16x32_f16(a1, b1, accp, 0, 0, 0);
      }
      const int ac = at * 16 + lo;
#pragma unroll
      for (int i = 0; i < 4; ++i)
        o1_lds[(4 * g + i) * 40 + ac] = (_Float16)fmaxf(accp[i] + bp1v, 0.f);
    }
    __syncthreads();   // o1 complete
    if (w < 2) { // stage-2: out_t = relu-done o1 @ Wp2 + bp2
      f16x8 a2 = *(const f16x8*)(o1_lds + lo * 40 + g * 8);
      f16x8 b2 = *(const f16x8*)(Wp2T + (at * 16 + lo) * 32 + g * 8);
      f32x4 accl = {};
      accl = __builtin_amdgcn_mfma_f32_16x16x32_f16(a2, b2, accl, 0, 0, 0);
#pragma unroll
      for (int i = 0; i < 4; ++i) {
        const int m = 4 * g + i;
        out[((size_t)(b0 + m) * T_ + t) * A_ + at * 16 + lo] = accl[i] + bp2v;
      }
    }
    // no 3rd barrier: next o1 write is after the next step's first barrier
  }
}

// ---------------- launch ----------------

extern "C" void kernel_launch(void* const* d_in, const int* in_sizes, int n_in,
                              void* d_out, int out_size, void* d_ws, size_t ws_size,
                              hipStream_t stream) {
  const float* latent = (const float*)d_in[0];
  const int*   target = (const int*)d_in[1];
  const float* embed  = (const float*)d_in[2];
  const float* W_ih   = (const float*)d_in[3];
  const float* b_ih   = (const float*)d_in[4];
  const float* W_hh   = (const float*)d_in[5];
  const float* b_hh   = (const float*)d_in[6];
  const float* Wd0    = (const float*)d_in[7];
  const float* bd0    = (const float*)d_in[8];
  const float* Wd1    = (const float*)d_in[9];
  const float* bd1    = (const float*)d_in[10];
  const float* Wd2    = (const float*)d_in[11];
  const float* bd2    = (const float*)d_in[12];
  const float* Wp1    = (const float*)d_in[13];
  const float* bp1    = (const float*)d_in[14];
  const float* Wp2    = (const float*)d_in[15];
  const float* bp2    = (const float*)d_in[16];
  float* out = (float*)d_out;

  char* ws = (char*)d_ws;
  size_t off = 0;
  auto carve = [&](size_t bytes) { char* p = ws + off; off += (bytes + 255) & ~(size_t)255; return p; };
  _Float16* latent16 = (_Float16*)carve((size_t)B_ * L_ * 2);
  _Float16* Whh16    = (_Float16*)carve((size_t)768 * H_ * 2);
  _Float16* Wd0T     = (_Float16*)carve(256 * 128 * 2);
  _Float16* Wd1T     = (_Float16*)carve(256 * 256 * 2);
  _Float16* Wd2T     = (_Float16*)carve(256 * 256 * 2);
  _Float16* Wp1T     = (_Float16*)carve(32 * 256 * 2);
  _Float16* Wp2T     = (_Float16*)carve(32 * 32 * 2);
  _Float16* G4       = (_Float16*)carve(A_ * 256 * 4 * 2);

  prep_convert<<<1024, 256, 0, stream>>>(latent, W_hh, latent16, Whh16);
  prep_transpose<<<256, 256, 0, stream>>>(Wd0, Wd1, Wd2, Wp1, Wp2, Wd0T, Wd1T, Wd2T, Wp1T, Wp2T);
  prep_g4<<<(A_ * 256 * 4 + 255) / 256, 256, 0, stream>>>(embed, W_ih, b_ih, b_hh, G4);
  decoder_main<<<B_ / BM, 256, 0, stream>>>(latent16, target, Whh16, G4,
                                            Wd0T, Wd1T, Wd2T, Wp1T, Wp2T,
                                            bd0, bd1, bd2, b_hh, bp1, bp2, out);
}